// Round 5
// baseline (1169.383 us; speedup 1.0000x reference)
//
#include <hip/hip_runtime.h>
#include <math.h>

// Shapes (fixed by setup_inputs)
#define BATCH 8
#define TSEQ 2048
#define CIN 3
#define WIN 5
#define LSEQ 2044          // T - WIN + 1
#define LH 2045            // LSEQ + 1 (cls token appended)
#define DIM 128
#define DEPTH 4
#define DIN 256            // d_inner
#define NH 4               // heads
#define PDIM 64            // headdim
#define NSTATE 64          // d_state
#define CONVD 384          // d_inner + 2*d_state
#define DPROJ 644          // 2*d_inner + 2*d_state + nheads
#define QC 64              // chunk length
#define NCH 32             // number of chunks (32*64 = 2048 >= 2045)
#define LDP 68             // padded LDS row stride (17 float4s; bank-spread)
#define FTR 32             // tokens per k_front block

__device__ __forceinline__ float sigmoidf_(float x){ return 1.f/(1.f+__expf(-x)); }
__device__ __forceinline__ float siluf_(float x){ return x*sigmoidf_(x); }

// ---------------------------------------------------------------- front MLP
// grid: BATCH*64 + 1, block 256. 32 tokens/block; w2 half-rows register-cached.
__global__ void __launch_bounds__(256) k_front(
    const float* __restrict__ x, const float* __restrict__ w1,
    const float* __restrict__ b1, const float* __restrict__ w2,
    const float* __restrict__ b2, const float* __restrict__ cls,
    float* __restrict__ h) {
  int t = threadIdx.x;
  if (blockIdx.x == BATCH*64) {              // cls rows
    if (t < DIM) {
      float cv = cls[t];
      for (int b = 0; b < BATCH; ++b) h[((size_t)b*LH + LSEQ)*DIM + t] = cv;
    }
    return;
  }
  int b = blockIdx.x >> 6;
  int c0 = (blockIdx.x & 63) * FTR;
  __shared__ float xs[(FTR+4)*CIN];                  // 108
  __shared__ float w1s[DIM*17];                      // stride 17: 2-way banks = free
  __shared__ __align__(16) float h1s[FTR][DIM];      // 16 KB
  __shared__ float part[FTR][DIM][2];                // 32 KB
  for (int i = t; i < (FTR+4)*CIN; i += 256) {
    int row = c0 + i/3, ch = i - (i/3)*3;
    xs[i] = (row < TSEQ) ? x[(size_t)b*TSEQ*CIN + (size_t)row*CIN + ch] : 0.f;
  }
  for (int i = t; i < DIM*15; i += 256) {
    int j = i/15, k = i - j*15;
    w1s[j*17+k] = w1[i];
  }
  __syncthreads();
  {
    int j = t & 127, rh = t >> 7;
    float bias = b1[j];
    const float* wr = &w1s[j*17];
    for (int r = rh*16; r < rh*16+16; ++r) {
      float a = bias;
#pragma unroll
      for (int k = 0; k < 15; ++k) a += xs[r*3+k]*wr[k];
      h1s[r][j] = 0.5f*a*(1.f + erff(a*0.70710678118654752f));  // exact gelu
    }
  }
  __syncthreads();
  {
    int j = t & 127, hf = t >> 7;
    float4 wv[16];                                   // 64-float w2 half-row in regs
    const float4* w2r = (const float4*)(w2 + (size_t)j*DIM + hf*64);
#pragma unroll
    for (int k4 = 0; k4 < 16; ++k4) wv[k4] = w2r[k4];
#pragma unroll 2
    for (int r = 0; r < FTR; ++r) {
      const float4* hr = (const float4*)&h1s[r][hf*64];
      float acc = 0.f;
#pragma unroll
      for (int k4 = 0; k4 < 16; ++k4) {
        float4 hv = hr[k4];                          // broadcast read: free
        acc += wv[k4].x*hv.x + wv[k4].y*hv.y + wv[k4].z*hv.z + wv[k4].w*hv.w;
      }
      part[r][j][hf] = acc;
    }
  }
  __syncthreads();
  if (t < DIM) {
    float bias = b2[t];
    for (int r = 0; r < FTR; ++r) {
      int l = c0 + r;
      if (l < LSEQ) h[((size_t)b*LH + l)*DIM + t] = part[r][t][0] + part[r][t][1] + bias;
    }
  }
}

// ---------------------------------------------------------------- in_proj (+ dt softplus)
// grid: BATCH*128, block 256. J=3 register tile: thread owns j in {t, t+256, t+512}.
#define TR2 16
__global__ void __launch_bounds__(256) k_inproj(
    const float* __restrict__ h, const float* __restrict__ w,
    const float* __restrict__ dtb, float* __restrict__ zx) {
  const int nblk_l = (LH + TR2 - 1) / TR2;   // 128
  int b = blockIdx.x / nblk_l;
  int l0 = (blockIdx.x % nblk_l) * TR2;
  int t = threadIdx.x;
  __shared__ __align__(16) float hs[TR2][DIM];
  for (int i = t; i < TR2*DIM; i += 256) {
    int r = i >> 7, k = i & 127;
    int l = l0 + r;
    hs[r][k] = (l < LH) ? h[((size_t)b*LH + l)*DIM + k] : 0.f;
  }
  __syncthreads();
  bool j2ok = (t < DPROJ - 512);             // t < 132
  float acc[3][TR2];
#pragma unroll
  for (int jj = 0; jj < 3; ++jj)
#pragma unroll
    for (int r = 0; r < TR2; ++r) acc[jj][r] = 0.f;
  const float4* wp0 = (const float4*)(w + (size_t)t*DIM);
  const float4* wp1 = (const float4*)(w + (size_t)(t+256)*DIM);
  const float4* wp2 = (const float4*)(w + (size_t)(j2ok ? t+512 : t)*DIM);
#pragma unroll 1
  for (int k4 = 0; k4 < 32; ++k4) {          // unroll 1: keep VGPRs < spill (see R2)
    float4 wa = wp0[k4], wb = wp1[k4], wc = wp2[k4];
#pragma unroll
    for (int r = 0; r < TR2; ++r) {
      float4 hv = ((const float4*)&hs[r][0])[k4];   // broadcast read
      acc[0][r] += wa.x*hv.x + wa.y*hv.y + wa.z*hv.z + wa.w*hv.w;
      acc[1][r] += wb.x*hv.x + wb.y*hv.y + wb.z*hv.z + wb.w*hv.w;
      acc[2][r] += wc.x*hv.x + wc.y*hv.y + wc.z*hv.z + wc.w*hv.w;
    }
  }
  bool isdt = j2ok && (t >= 128);            // j2 = t+512 >= 640
  float bias2 = isdt ? dtb[t - 128] : 0.f;
  int lmax = (LH - l0 < TR2) ? (LH - l0) : TR2;
  for (int r = 0; r < lmax; ++r) {
    size_t row = ((size_t)b*LH + l0 + r)*DPROJ;
    zx[row + t]       = acc[0][r];
    zx[row + t + 256] = acc[1][r];
    if (j2ok) {
      float v = acc[2][r];
      if (isdt) { v += bias2; v = (v > 20.f) ? v : log1pf(__expf(v)); } // softplus
      zx[row + t + 512] = v;
    }
  }
}

// ---------------------------------------------------------------- causal dwconv + silu
__global__ void k_conv(const float* __restrict__ zx, const float* __restrict__ cw,
                       const float* __restrict__ cb, float* __restrict__ xbc) {
  size_t idx = (size_t)blockIdx.x*blockDim.x + threadIdx.x;
  const size_t total = (size_t)BATCH*LH*CONVD;
  if (idx >= total) return;
  int c = (int)(idx % CONVD);
  size_t bl = idx / CONVD;
  int l = (int)(bl % LH); int b = (int)(bl / LH);
  float acc = cb[c];
#pragma unroll
  for (int k = 0; k < 4; ++k) {
    int tin = l - 3 + k;
    if (tin >= 0) acc += zx[((size_t)b*LH + tin)*DPROJ + DIN + c] * cw[c*4 + k];
  }
  xbc[idx] = siluf_(acc);
}

// ---------------------------------------------------------------- chunked SSD, phase A:
// per-chunk local state G (stored transposed: flat[n*64+p] = H_local[p][n]) + chunk decay
// grid: BATCH*NH*NCH = 1024, block 256
__global__ void __launch_bounds__(256) k_chunk_state(
    const float* __restrict__ zx, const float* __restrict__ xbc,
    const float* __restrict__ A_log, float* __restrict__ G, float* __restrict__ dec) {
  int blk = blockIdx.x;
  int c = blk & (NCH-1), hd = (blk >> 5) & 3, b = blk >> 7;
  int t0 = c*QC;
  int tid = threadIdx.x;
  float A = -__expf(A_log[hd]);
  __shared__ float xs[QC*PDIM];     // [s][p]
  __shared__ float Bs[QC*NSTATE];   // [s][n]
  __shared__ float coef[QC];
  if (tid < 64) {
    int tg = t0 + tid;
    float dtv = (tg < LH) ? zx[((size_t)b*LH + tg)*DPROJ + 640 + hd] : 0.f;
    float s = dtv;
#pragma unroll
    for (int off = 1; off < 64; off <<= 1) {
      float u = __shfl_up(s, off);
      if (tid >= off) s += u;
    }
    float cq = __shfl(s, 63);
    coef[tid] = __expf(A*(cq - s)) * dtv;
    if (tid == 63) dec[blk] = __expf(A * s);
  }
  for (int i = tid; i < QC*64; i += 256) {
    int s = i >> 6, j = i & 63;
    int tg = t0 + s;
    float xv = 0.f, bv = 0.f;
    if (tg < LH) {
      size_t row = ((size_t)b*LH + tg)*CONVD;
      xv = xbc[row + hd*PDIM + j];
      bv = xbc[row + DIN + j];
    }
    xs[i] = xv; Bs[i] = bv;
  }
  __syncthreads();
  int n = tid >> 2, q = tid & 3;            // thread owns (n, p in [q*16, q*16+16))
  float4 acc[4];
#pragma unroll
  for (int i4 = 0; i4 < 4; ++i4) acc[i4] = make_float4(0.f,0.f,0.f,0.f);
  const float4* xs4 = (const float4*)xs;
#pragma unroll 4
  for (int s = 0; s < QC; ++s) {            // capped unroll: keep VGPRs < spill
    float cb_ = coef[s] * Bs[s*64 + n];
#pragma unroll
    for (int i4 = 0; i4 < 4; ++i4) {
      float4 xv = xs4[s*16 + q*4 + i4];
      acc[i4].x += cb_*xv.x; acc[i4].y += cb_*xv.y;
      acc[i4].z += cb_*xv.z; acc[i4].w += cb_*xv.w;
    }
  }
  float4* gp = (float4*)(G + (size_t)blk*4096 + n*64 + q*16);
#pragma unroll
  for (int i4 = 0; i4 < 4; ++i4) gp[i4] = acc[i4];
}

// ---------------------------------------------------------------- phase B: inter-chunk
// recurrence. Stores carry-in state per chunk. grid 32*4=128, block 256, 4 floats/thread
__global__ void __launch_bounds__(256) k_combine(
    const float* __restrict__ G, const float* __restrict__ dec, float* __restrict__ Hin) {
  int bh = blockIdx.x >> 2, esp = blockIdx.x & 3;
  int e = esp*1024 + threadIdx.x*4;
  size_t base0 = (size_t)bh*NCH*4096 + e;
  float4 H = make_float4(0.f,0.f,0.f,0.f);
  float4 g = *(const float4*)(G + base0);
  float d = dec[bh*NCH];
  for (int c = 0; c < NCH; ++c) {
    float4 gn = make_float4(0.f,0.f,0.f,0.f); float dn = 0.f;
    if (c + 1 < NCH) {
      gn = *(const float4*)(G + base0 + (size_t)(c+1)*4096);
      dn = dec[bh*NCH + c + 1];
    }
    *(float4*)(Hin + base0 + (size_t)c*4096) = H;   // carry-in for chunk c
    H.x = H.x*d + g.x; H.y = H.y*d + g.y; H.z = H.z*d + g.z; H.w = H.w*d + g.w;
    g = gn; d = dn;
  }
}

// ---------------------------------------------------------------- phase C: chunk output
// y[t][p] = sum_{s<=t} exp(A(cum_t-cum_s))dt_s (C_t.B_s) x_s[p] + exp(A cum_t) C_t.H_in[p,:]
// grid 1024, block 256. Tiles: t = tr+16j (tr=tid>>4), p = tc*4..+3 (tc=tid&15), s' = tc+16i
__global__ void __launch_bounds__(256) k_chunk_out(
    const float* __restrict__ zx, const float* __restrict__ xbc,
    const float* __restrict__ A_log, const float* __restrict__ Hin,
    float* __restrict__ y) {
  int blk = blockIdx.x;
  int c = blk & (NCH-1), hd = (blk >> 5) & 3, b = blk >> 7;
  int t0 = c*QC;
  int tid = threadIdx.x;
  int tr = tid >> 4, tc = tid & 15;
  float A = -__expf(A_log[hd]);
  __shared__ __align__(16) float SA[QC*LDP];   // B, then X
  __shared__ __align__(16) float SB[QC*LDP];   // C
  __shared__ __align__(16) float SC[QC*LDP];   // M, then HT
  __shared__ float cum[QC], dts[QC], pref[QC];
  if (tid < 64) {
    int tg = t0 + tid;
    float dtv = (tg < LH) ? zx[((size_t)b*LH + tg)*DPROJ + 640 + hd] : 0.f;
    float s = dtv;
#pragma unroll
    for (int off = 1; off < 64; off <<= 1) {
      float u = __shfl_up(s, off);
      if (tid >= off) s += u;
    }
    dts[tid] = dtv; cum[tid] = s; pref[tid] = __expf(A*s);
  }
  for (int i = tid; i < QC*64; i += 256) {
    int s = i >> 6, j = i & 63;
    int tg = t0 + s;
    float bv = 0.f, cv = 0.f;
    if (tg < LH) {
      size_t row = ((size_t)b*LH + tg)*CONVD;
      bv = xbc[row + DIN + j];
      cv = xbc[row + DIN + NSTATE + j];
    }
    SA[s*LDP + j] = bv; SB[s*LDP + j] = cv;
  }
  __syncthreads();
  // ---- S = C B^T  (tile: t = tr+16j, s' = tc+16i)
  float S[4][4];
#pragma unroll
  for (int j = 0; j < 4; ++j)
#pragma unroll
    for (int i = 0; i < 4; ++i) S[j][i] = 0.f;
  const float4* SA4 = (const float4*)SA;
  const float4* SB4 = (const float4*)SB;
#pragma unroll 2
  for (int n4 = 0; n4 < 16; ++n4) {         // capped unroll: keep VGPRs < spill
    float4 cv[4], bv[4];
#pragma unroll
    for (int j = 0; j < 4; ++j) cv[j] = SB4[(tr + 16*j)*(LDP/4) + n4];
#pragma unroll
    for (int i = 0; i < 4; ++i) bv[i] = SA4[(tc + 16*i)*(LDP/4) + n4];
#pragma unroll
    for (int j = 0; j < 4; ++j)
#pragma unroll
      for (int i = 0; i < 4; ++i)
        S[j][i] += cv[j].x*bv[i].x + cv[j].y*bv[i].y + cv[j].z*bv[i].z + cv[j].w*bv[i].w;
  }
  __syncthreads();
  // ---- masked decay -> M in SC; reload X into SA
#pragma unroll
  for (int j = 0; j < 4; ++j) {
    int t = tr + 16*j;
#pragma unroll
    for (int i = 0; i < 4; ++i) {
      int s = tc + 16*i;
      float m = 0.f;
      if (s <= t) m = S[j][i] * __expf(A*(cum[t] - cum[s])) * dts[s];
      SC[t*LDP + s] = m;
    }
  }
  for (int i = tid; i < QC*64; i += 256) {
    int s = i >> 6, j = i & 63;
    int tg = t0 + s;
    SA[s*LDP + j] = (tg < LH) ? xbc[((size_t)b*LH + tg)*CONVD + hd*PDIM + j] : 0.f;
  }
  __syncthreads();
  // ---- Y1 = M X  (tile: t = tr+16j, p = tc*4..+3)
  float4 y1[4];
#pragma unroll
  for (int j = 0; j < 4; ++j) y1[j] = make_float4(0.f,0.f,0.f,0.f);
  const float4* SC4 = (const float4*)SC;
#pragma unroll 2
  for (int s4 = 0; s4 < 16; ++s4) {         // capped unroll
    float4 mj[4], xk[4];
#pragma unroll
    for (int j = 0; j < 4; ++j) mj[j] = SC4[(tr + 16*j)*(LDP/4) + s4];
#pragma unroll
    for (int k = 0; k < 4; ++k) xk[k] = SA4[(s4*4 + k)*(LDP/4) + tc];
#pragma unroll
    for (int j = 0; j < 4; ++j) {
      y1[j].x += mj[j].x*xk[0].x + mj[j].y*xk[1].x + mj[j].z*xk[2].x + mj[j].w*xk[3].x;
      y1[j].y += mj[j].x*xk[0].y + mj[j].y*xk[1].y + mj[j].z*xk[2].y + mj[j].w*xk[3].y;
      y1[j].z += mj[j].x*xk[0].z + mj[j].y*xk[1].z + mj[j].z*xk[2].z + mj[j].w*xk[3].z;
      y1[j].w += mj[j].x*xk[0].w + mj[j].y*xk[1].w + mj[j].z*xk[2].w + mj[j].w*xk[3].w;
    }
  }
  __syncthreads();
  // ---- load HT (flat [n*64+p]) into SC
  size_t hbase = (size_t)blk*4096;
  for (int i = tid; i < 4096; i += 256) SC[(i >> 6)*LDP + (i & 63)] = Hin[hbase + i];
  __syncthreads();
  // ---- Y2 = C H_in^T  (reduction over n)
  float4 y2[4];
#pragma unroll
  for (int j = 0; j < 4; ++j) y2[j] = make_float4(0.f,0.f,0.f,0.f);
#pragma unroll 2
  for (int n4 = 0; n4 < 16; ++n4) {         // capped unroll
    float4 cj[4], hk[4];
#pragma unroll
    for (int j = 0; j < 4; ++j) cj[j] = SB4[(tr + 16*j)*(LDP/4) + n4];
#pragma unroll
    for (int k = 0; k < 4; ++k) hk[k] = SC4[(n4*4 + k)*(LDP/4) + tc];
#pragma unroll
    for (int j = 0; j < 4; ++j) {
      y2[j].x += cj[j].x*hk[0].x + cj[j].y*hk[1].x + cj[j].z*hk[2].x + cj[j].w*hk[3].x;
      y2[j].y += cj[j].x*hk[0].y + cj[j].y*hk[1].y + cj[j].z*hk[2].y + cj[j].w*hk[3].y;
      y2[j].z += cj[j].x*hk[0].z + cj[j].y*hk[1].z + cj[j].z*hk[2].z + cj[j].w*hk[3].z;
      y2[j].w += cj[j].x*hk[0].w + cj[j].y*hk[1].w + cj[j].z*hk[2].w + cj[j].w*hk[3].w;
    }
  }
#pragma unroll
  for (int j = 0; j < 4; ++j) {
    int t = tr + 16*j, tg = t0 + t;
    if (tg < LH) {
      float pr = pref[t];
      float4 o;
      o.x = y1[j].x + pr*y2[j].x;
      o.y = y1[j].y + pr*y2[j].y;
      o.z = y1[j].z + pr*y2[j].z;
      o.w = y1[j].w + pr*y2[j].w;
      *(float4*)(y + ((size_t)b*LH + tg)*DIN + hd*PDIM + tc*4) = o;
    }
  }
}

// ---------------------------------------------------------------- gate + rmsnorm + out_proj
// grid: BATCH*256, block 256. Matmul: thread owns 2 j's x one k-quarter; acc[2][8].
#define TR5 8
__global__ void __launch_bounds__(256) k_out(
    const float* __restrict__ y, const float* __restrict__ xbc,
    const float* __restrict__ zx, const float* __restrict__ Dh,
    const float* __restrict__ nw, const float* __restrict__ ow,
    float* __restrict__ h) {
  const int nblk_l = (LH + TR5 - 1) / TR5;    // 256
  int b = blockIdx.x / nblk_l;
  int l0 = (blockIdx.x % nblk_l) * TR5;
  int t = threadIdx.x;
  __shared__ __align__(16) float yv[TR5][DIN];
  __shared__ float part[4][TR5][DIM];          // 16 KB quarter partials
  __shared__ float red[TR5][4];
  __shared__ float rs[TR5];
  int c = t;
  int hd = c >> 6;
  float dcoef = Dh[hd];
  float nwc = nw[c];
  float v[TR5];
#pragma unroll
  for (int r = 0; r < TR5; ++r) {
    int l = l0 + r;
    float val = 0.f;
    if (l < LH) {
      size_t row = (size_t)b*LH + l;
      float ys = y[row*DIN + c];
      float xh = xbc[row*CONVD + c];
      float z  = zx[row*DPROJ + c];
      val = (ys + dcoef*xh) * siluf_(z);
    }
    v[r] = val;
  }
  int wave = t >> 6, lane = t & 63;
#pragma unroll
  for (int r = 0; r < TR5; ++r) {
    float sq = v[r]*v[r];
    for (int off = 32; off > 0; off >>= 1) sq += __shfl_down(sq, off);
    if (lane == 0) red[r][wave] = sq;
  }
  __syncthreads();
  if (t < TR5) {
    float sm = red[t][0]+red[t][1]+red[t][2]+red[t][3];
    rs[t] = rsqrtf(sm/(float)DIN + 1e-5f);
  }
  __syncthreads();
#pragma unroll
  for (int r = 0; r < TR5; ++r) yv[r][c] = v[r] * rs[r] * nwc;
  __syncthreads();
  // matmul: jp = t&63 -> j in {2jp, 2jp+1}; q = t>>6 -> k in [q*64, q*64+64)
  int jp = t & 63, q = t >> 6;
  int j0 = jp*2;
  float acc[2][TR5];
#pragma unroll
  for (int jj = 0; jj < 2; ++jj)
#pragma unroll
    for (int r = 0; r < TR5; ++r) acc[jj][r] = 0.f;
  const float4* wr0 = (const float4*)(ow + (size_t)j0*DIN + q*64);
  const float4* wr1 = (const float4*)(ow + (size_t)(j0+1)*DIN + q*64);
#pragma unroll 2
  for (int k4 = 0; k4 < 16; ++k4) {
    float4 wa = wr0[k4], wb = wr1[k4];
#pragma unroll
    for (int r = 0; r < TR5; ++r) {
      float4 hv = ((const float4*)&yv[r][q*64])[k4];  // broadcast
      acc[0][r] += wa.x*hv.x + wa.y*hv.y + wa.z*hv.z + wa.w*hv.w;
      acc[1][r] += wb.x*hv.x + wb.y*hv.y + wb.z*hv.z + wb.w*hv.w;
    }
  }
#pragma unroll
  for (int r = 0; r < TR5; ++r) {
    part[q][r][j0]   = acc[0][r];
    part[q][r][j0+1] = acc[1][r];
  }
  __syncthreads();
  if (t < DIM) {
#pragma unroll 2
    for (int r = 0; r < TR5; ++r) {
      int l = l0 + r;
      if (l < LH)
        h[((size_t)b*LH + l)*DIM + t] =
            part[0][r][t] + part[1][r][t] + part[2][r][t] + part[3][r][t];
    }
  }
}

// ---------------------------------------------------------------- final LN + head
__global__ void k_head(const float* __restrict__ h, const float* __restrict__ lnw,
                       const float* __restrict__ lnb, const float* __restrict__ hw,
                       const float* __restrict__ hb, float* __restrict__ out) {
  int b = blockIdx.x; int t = threadIdx.x;
  __shared__ float red[2];
  int wave = t >> 6, lane = t & 63;
  float v = h[((size_t)b*LH + LSEQ)*DIM + t];
  float s = v;
  for (int off = 32; off > 0; off >>= 1) s += __shfl_down(s, off);
  if (lane == 0) red[wave] = s;
  __syncthreads();
  float mean = (red[0]+red[1]) / (float)DIM;
  __syncthreads();
  float d = v - mean; float sq = d*d;
  for (int off = 32; off > 0; off >>= 1) sq += __shfl_down(sq, off);
  if (lane == 0) red[wave] = sq;
  __syncthreads();
  float var = (red[0]+red[1]) / (float)DIM;
  float cn = d*rsqrtf(var + 1e-5f)*lnw[t] + lnb[t];
  float dot = cn*hw[t];
  __syncthreads();
  for (int off = 32; off > 0; off >>= 1) dot += __shfl_down(dot, off);
  if (lane == 0) red[wave] = dot;
  __syncthreads();
  if (t == 0) out[b] = red[0]+red[1] + hb[0];
}

// ---------------------------------------------------------------- h -> d_out copy
__global__ void k_copy(const float* __restrict__ src, float* __restrict__ dst, long n4) {
  long i = (long)blockIdx.x*blockDim.x + threadIdx.x;
  if (i < n4) ((float4*)dst)[i] = ((const float4*)src)[i];
}

extern "C" void kernel_launch(void* const* d_in, const int* in_sizes, int n_in,
                              void* d_out, int out_size, void* d_ws, size_t ws_size,
                              hipStream_t stream) {
  const float* x     = (const float*)d_in[0];
  const float* w1    = (const float*)d_in[1];
  const float* b1    = (const float*)d_in[2];
  const float* w2    = (const float*)d_in[3];
  const float* b2    = (const float*)d_in[4];
  const float* cls   = (const float*)d_in[5];
  const float* inw   = (const float*)d_in[6];   // (4, 644, 128)
  const float* cw    = (const float*)d_in[7];   // (4, 384, 4)
  const float* cb    = (const float*)d_in[8];   // (4, 384)
  const float* dtb   = (const float*)d_in[9];   // (4, 4)
  const float* Alog  = (const float*)d_in[10];  // (4, 4)
  const float* Dh    = (const float*)d_in[11];  // (4, 4)
  const float* nw    = (const float*)d_in[12];  // (4, 256)
  const float* ow    = (const float*)d_in[13];  // (4, 128, 256)
  const float* lnw   = (const float*)d_in[14];
  const float* lnb   = (const float*)d_in[15];
  const float* hw    = (const float*)d_in[16];
  const float* hb    = (const float*)d_in[17];

  float* ws   = (float*)d_ws;
  float* hbuf = ws;                                   // 2,094,080
  float* zx   = hbuf + (size_t)BATCH*LH*DIM;          // 10,535,840
  float* xbc  = zx   + (size_t)BATCH*LH*DPROJ;        // 6,282,240
  float* ybuf = xbc  + (size_t)BATCH*LH*CONVD;        // 4,194,304 (G aliases ybuf)
  float* G    = ybuf;                                 //   (consumed before y written)
  float* Hin  = ybuf + 4194304;                       // 4,194,304
  float* dec  = Hin  + 4194304;                       // 1,024
  // total: 27,301,792 floats = 104.2 MiB

  k_front<<<BATCH*64 + 1, 256, 0, stream>>>(x, w1, b1, w2, b2, cls, hbuf);

  for (int i = 0; i < DEPTH; ++i) {
    k_inproj<<<BATCH*((LH+TR2-1)/TR2), 256, 0, stream>>>(
        hbuf, inw + (size_t)i*DPROJ*DIM, dtb + i*NH, zx);
    {
      long total = (long)BATCH*LH*CONVD;
      k_conv<<<(int)((total + 255)/256), 256, 0, stream>>>(
          zx, cw + (size_t)i*CONVD*4, cb + (size_t)i*CONVD, xbc);
    }
    k_chunk_state<<<BATCH*NH*NCH, 256, 0, stream>>>(zx, xbc, Alog + i*NH, G, dec);
    k_combine<<<BATCH*NH*4, 256, 0, stream>>>(G, dec, Hin);
    k_chunk_out<<<BATCH*NH*NCH, 256, 0, stream>>>(zx, xbc, Alog + i*NH, Hin, ybuf);
    k_out<<<BATCH*((LH+TR5-1)/TR5), 256, 0, stream>>>(
        ybuf, xbc, zx, Dh + i*NH, nw + (size_t)i*DIN, ow + (size_t)i*DIM*DIN, hbuf);
  }

  k_head<<<BATCH, 128, 0, stream>>>(hbuf, lnw, lnb, hw, hb, (float*)d_out);
  {
    long n4 = (long)BATCH*LH*DIM/4;
    k_copy<<<(int)((n4 + 255)/256), 256, 0, stream>>>(hbuf, (float*)d_out + 8, n4);
  }
}

// Round 6
// 1010.314 us; speedup vs baseline: 1.1574x; 1.1574x over previous
//
#include <hip/hip_runtime.h>
#include <math.h>

// Shapes (fixed by setup_inputs)
#define BATCH 8
#define TSEQ 2048
#define CIN 3
#define WIN 5
#define LSEQ 2044          // T - WIN + 1
#define LH 2045            // LSEQ + 1 (cls token appended)
#define DIM 128
#define DEPTH 4
#define DIN 256            // d_inner
#define NH 4               // heads
#define PDIM 64            // headdim
#define NSTATE 64          // d_state
#define CONVD 384          // d_inner + 2*d_state
#define DPROJ 644          // 2*d_inner + 2*d_state + nheads
#define QC 64              // chunk length
#define NCH 32             // number of chunks (32*64 = 2048 >= 2045)
#define LDP 68             // padded LDS row stride (17 float4s; bank-spread)
#define FTR 32             // tokens per k_front block

__device__ __forceinline__ float sigmoidf_(float x){ return 1.f/(1.f+__expf(-x)); }
__device__ __forceinline__ float siluf_(float x){ return x*sigmoidf_(x); }

// ---------------------------------------------------------------- front MLP
// grid: BATCH*64 + 1, block 256. 32 tokens/block; w2 half-rows register-cached.
__global__ void __launch_bounds__(256) k_front(
    const float* __restrict__ x, const float* __restrict__ w1,
    const float* __restrict__ b1, const float* __restrict__ w2,
    const float* __restrict__ b2, const float* __restrict__ cls,
    float* __restrict__ h) {
  int t = threadIdx.x;
  if (blockIdx.x == BATCH*64) {              // cls rows
    if (t < DIM) {
      float cv = cls[t];
      for (int b = 0; b < BATCH; ++b) h[((size_t)b*LH + LSEQ)*DIM + t] = cv;
    }
    return;
  }
  int b = blockIdx.x >> 6;
  int c0 = (blockIdx.x & 63) * FTR;
  __shared__ float xs[(FTR+4)*CIN];                  // 108
  __shared__ float w1s[DIM*17];                      // stride 17: 2-way banks = free
  __shared__ __align__(16) float h1s[FTR][DIM];      // 16 KB
  __shared__ float part[FTR][DIM][2];                // 32 KB
  for (int i = t; i < (FTR+4)*CIN; i += 256) {
    int row = c0 + i/3, ch = i - (i/3)*3;
    xs[i] = (row < TSEQ) ? x[(size_t)b*TSEQ*CIN + (size_t)row*CIN + ch] : 0.f;
  }
  for (int i = t; i < DIM*15; i += 256) {
    int j = i/15, k = i - j*15;
    w1s[j*17+k] = w1[i];
  }
  __syncthreads();
  {
    int j = t & 127, rh = t >> 7;
    float bias = b1[j];
    const float* wr = &w1s[j*17];
    for (int r = rh*16; r < rh*16+16; ++r) {
      float a = bias;
#pragma unroll
      for (int k = 0; k < 15; ++k) a += xs[r*3+k]*wr[k];
      h1s[r][j] = 0.5f*a*(1.f + erff(a*0.70710678118654752f));  // exact gelu
    }
  }
  __syncthreads();
  {
    int j = t & 127, hf = t >> 7;
    float4 wv[16];                                   // 64-float w2 half-row in regs
    const float4* w2r = (const float4*)(w2 + (size_t)j*DIM + hf*64);
#pragma unroll
    for (int k4 = 0; k4 < 16; ++k4) wv[k4] = w2r[k4];
#pragma unroll 2
    for (int r = 0; r < FTR; ++r) {
      const float4* hr = (const float4*)&h1s[r][hf*64];
      float acc = 0.f;
#pragma unroll
      for (int k4 = 0; k4 < 16; ++k4) {
        float4 hv = hr[k4];                          // broadcast read: free
        acc += wv[k4].x*hv.x + wv[k4].y*hv.y + wv[k4].z*hv.z + wv[k4].w*hv.w;
      }
      part[r][j][hf] = acc;
    }
  }
  __syncthreads();
  if (t < DIM) {
    float bias = b2[t];
    for (int r = 0; r < FTR; ++r) {
      int l = c0 + r;
      if (l < LSEQ) h[((size_t)b*LH + l)*DIM + t] = part[r][t][0] + part[r][t][1] + bias;
    }
  }
}

// ---------------------------------------------------------------- in_proj (+ dt softplus)
// grid: BATCH*128, block 256. J=3 register tile: thread owns j in {t, t+256, t+512}.
// NOTE (R5 post-mortem): epilogue MUST be compile-time unrolled — a runtime
// trip count makes acc[][] dynamically indexed -> scratch spill (VGPR 44,
// WRITE 120 MB). Keep #pragma unroll + guard.
#define TR2 16
__global__ void __launch_bounds__(256) k_inproj(
    const float* __restrict__ h, const float* __restrict__ w,
    const float* __restrict__ dtb, float* __restrict__ zx) {
  const int nblk_l = (LH + TR2 - 1) / TR2;   // 128
  int b = blockIdx.x / nblk_l;
  int l0 = (blockIdx.x % nblk_l) * TR2;
  int t = threadIdx.x;
  __shared__ __align__(16) float hs[TR2][DIM];
  for (int i = t; i < TR2*DIM; i += 256) {
    int r = i >> 7, k = i & 127;
    int l = l0 + r;
    hs[r][k] = (l < LH) ? h[((size_t)b*LH + l)*DIM + k] : 0.f;
  }
  __syncthreads();
  bool j2ok = (t < DPROJ - 512);             // t < 132
  float acc[3][TR2];
#pragma unroll
  for (int jj = 0; jj < 3; ++jj)
#pragma unroll
    for (int r = 0; r < TR2; ++r) acc[jj][r] = 0.f;
  const float4* wp0 = (const float4*)(w + (size_t)t*DIM);
  const float4* wp1 = (const float4*)(w + (size_t)(t+256)*DIM);
  const float4* wp2 = (const float4*)(w + (size_t)(j2ok ? t+512 : t)*DIM);
#pragma unroll 2
  for (int k4 = 0; k4 < 32; ++k4) {          // capped unroll: VGPRs < spill cliff
    float4 wa = wp0[k4], wb = wp1[k4], wc = wp2[k4];
#pragma unroll
    for (int r = 0; r < TR2; ++r) {
      float4 hv = ((const float4*)&hs[r][0])[k4];   // broadcast read
      acc[0][r] += wa.x*hv.x + wa.y*hv.y + wa.z*hv.z + wa.w*hv.w;
      acc[1][r] += wb.x*hv.x + wb.y*hv.y + wb.z*hv.z + wb.w*hv.w;
      acc[2][r] += wc.x*hv.x + wc.y*hv.y + wc.z*hv.z + wc.w*hv.w;
    }
  }
  bool isdt = j2ok && (t >= 128);            // j2 = t+512 >= 640
  float bias2 = isdt ? dtb[t - 128] : 0.f;
#pragma unroll
  for (int r = 0; r < TR2; ++r) {            // compile-time: acc stays in VGPRs
    int l = l0 + r;
    if (l >= LH) continue;
    size_t row = ((size_t)b*LH + l)*DPROJ;
    zx[row + t]       = acc[0][r];
    zx[row + t + 256] = acc[1][r];
    if (j2ok) {
      float v = acc[2][r];
      if (isdt) { v += bias2; v = (v > 20.f) ? v : log1pf(__expf(v)); } // softplus
      zx[row + t + 512] = v;
    }
  }
}

// ---------------------------------------------------------------- causal dwconv + silu
__global__ void k_conv(const float* __restrict__ zx, const float* __restrict__ cw,
                       const float* __restrict__ cb, float* __restrict__ xbc) {
  size_t idx = (size_t)blockIdx.x*blockDim.x + threadIdx.x;
  const size_t total = (size_t)BATCH*LH*CONVD;
  if (idx >= total) return;
  int c = (int)(idx % CONVD);
  size_t bl = idx / CONVD;
  int l = (int)(bl % LH); int b = (int)(bl / LH);
  float acc = cb[c];
#pragma unroll
  for (int k = 0; k < 4; ++k) {
    int tin = l - 3 + k;
    if (tin >= 0) acc += zx[((size_t)b*LH + tin)*DPROJ + DIN + c] * cw[c*4 + k];
  }
  xbc[idx] = siluf_(acc);
}

// ---------------------------------------------------------------- chunked SSD, phase A:
// per-chunk local state G (stored transposed: flat[n*64+p] = H_local[p][n]) + chunk decay
// grid: BATCH*NH*NCH = 1024, block 256
__global__ void __launch_bounds__(256) k_chunk_state(
    const float* __restrict__ zx, const float* __restrict__ xbc,
    const float* __restrict__ A_log, float* __restrict__ G, float* __restrict__ dec) {
  int blk = blockIdx.x;
  int c = blk & (NCH-1), hd = (blk >> 5) & 3, b = blk >> 7;
  int t0 = c*QC;
  int tid = threadIdx.x;
  float A = -__expf(A_log[hd]);
  __shared__ float xs[QC*PDIM];     // [s][p]
  __shared__ float Bs[QC*NSTATE];   // [s][n]
  __shared__ float coef[QC];
  if (tid < 64) {
    int tg = t0 + tid;
    float dtv = (tg < LH) ? zx[((size_t)b*LH + tg)*DPROJ + 640 + hd] : 0.f;
    float s = dtv;
#pragma unroll
    for (int off = 1; off < 64; off <<= 1) {
      float u = __shfl_up(s, off);
      if (tid >= off) s += u;
    }
    float cq = __shfl(s, 63);
    coef[tid] = __expf(A*(cq - s)) * dtv;
    if (tid == 63) dec[blk] = __expf(A * s);
  }
  for (int i = tid; i < QC*64; i += 256) {
    int s = i >> 6, j = i & 63;
    int tg = t0 + s;
    float xv = 0.f, bv = 0.f;
    if (tg < LH) {
      size_t row = ((size_t)b*LH + tg)*CONVD;
      xv = xbc[row + hd*PDIM + j];
      bv = xbc[row + DIN + j];
    }
    xs[i] = xv; Bs[i] = bv;
  }
  __syncthreads();
  int n = tid >> 2, q = tid & 3;            // thread owns (n, p in [q*16, q*16+16))
  float4 acc[4];
#pragma unroll
  for (int i4 = 0; i4 < 4; ++i4) acc[i4] = make_float4(0.f,0.f,0.f,0.f);
  const float4* xs4 = (const float4*)xs;
#pragma unroll 4
  for (int s = 0; s < QC; ++s) {            // capped unroll: keep VGPRs < spill
    float cb_ = coef[s] * Bs[s*64 + n];
#pragma unroll
    for (int i4 = 0; i4 < 4; ++i4) {
      float4 xv = xs4[s*16 + q*4 + i4];
      acc[i4].x += cb_*xv.x; acc[i4].y += cb_*xv.y;
      acc[i4].z += cb_*xv.z; acc[i4].w += cb_*xv.w;
    }
  }
  float4* gp = (float4*)(G + (size_t)blk*4096 + n*64 + q*16);
#pragma unroll
  for (int i4 = 0; i4 < 4; ++i4) gp[i4] = acc[i4];
}

// ---------------------------------------------------------------- phase B: inter-chunk
// recurrence. Stores carry-in state per chunk. grid 32*4=128, block 256, 4 floats/thread
__global__ void __launch_bounds__(256) k_combine(
    const float* __restrict__ G, const float* __restrict__ dec, float* __restrict__ Hin) {
  int bh = blockIdx.x >> 2, esp = blockIdx.x & 3;
  int e = esp*1024 + threadIdx.x*4;
  size_t base0 = (size_t)bh*NCH*4096 + e;
  float4 H = make_float4(0.f,0.f,0.f,0.f);
  float4 g = *(const float4*)(G + base0);
  float d = dec[bh*NCH];
  for (int c = 0; c < NCH; ++c) {
    float4 gn = make_float4(0.f,0.f,0.f,0.f); float dn = 0.f;
    if (c + 1 < NCH) {
      gn = *(const float4*)(G + base0 + (size_t)(c+1)*4096);
      dn = dec[bh*NCH + c + 1];
    }
    *(float4*)(Hin + base0 + (size_t)c*4096) = H;   // carry-in for chunk c
    H.x = H.x*d + g.x; H.y = H.y*d + g.y; H.z = H.z*d + g.z; H.w = H.w*d + g.w;
    g = gn; d = dn;
  }
}

// ---------------------------------------------------------------- phase C: chunk output
// y[t][p] = sum_{s<=t} exp(A(cum_t-cum_s))dt_s (C_t.B_s) x_s[p] + exp(A cum_t) C_t.H_in[p,:]
// grid 1024, block 256. Tiles: t = tr+16j (tr=tid>>4), p = tc*4..+3 (tc=tid&15), s' = tc+16i
__global__ void __launch_bounds__(256) k_chunk_out(
    const float* __restrict__ zx, const float* __restrict__ xbc,
    const float* __restrict__ A_log, const float* __restrict__ Hin,
    float* __restrict__ y) {
  int blk = blockIdx.x;
  int c = blk & (NCH-1), hd = (blk >> 5) & 3, b = blk >> 7;
  int t0 = c*QC;
  int tid = threadIdx.x;
  int tr = tid >> 4, tc = tid & 15;
  float A = -__expf(A_log[hd]);
  __shared__ __align__(16) float SA[QC*LDP];   // B, then X
  __shared__ __align__(16) float SB[QC*LDP];   // C
  __shared__ __align__(16) float SC[QC*LDP];   // M, then HT
  __shared__ float cum[QC], dts[QC], pref[QC];
  if (tid < 64) {
    int tg = t0 + tid;
    float dtv = (tg < LH) ? zx[((size_t)b*LH + tg)*DPROJ + 640 + hd] : 0.f;
    float s = dtv;
#pragma unroll
    for (int off = 1; off < 64; off <<= 1) {
      float u = __shfl_up(s, off);
      if (tid >= off) s += u;
    }
    dts[tid] = dtv; cum[tid] = s; pref[tid] = __expf(A*s);
  }
  for (int i = tid; i < QC*64; i += 256) {
    int s = i >> 6, j = i & 63;
    int tg = t0 + s;
    float bv = 0.f, cv = 0.f;
    if (tg < LH) {
      size_t row = ((size_t)b*LH + tg)*CONVD;
      bv = xbc[row + DIN + j];
      cv = xbc[row + DIN + NSTATE + j];
    }
    SA[s*LDP + j] = bv; SB[s*LDP + j] = cv;
  }
  __syncthreads();
  // ---- S = C B^T  (tile: t = tr+16j, s' = tc+16i)
  float S[4][4];
#pragma unroll
  for (int j = 0; j < 4; ++j)
#pragma unroll
    for (int i = 0; i < 4; ++i) S[j][i] = 0.f;
  const float4* SA4 = (const float4*)SA;
  const float4* SB4 = (const float4*)SB;
#pragma unroll 2
  for (int n4 = 0; n4 < 16; ++n4) {         // capped unroll: keep VGPRs < spill
    float4 cv[4], bv[4];
#pragma unroll
    for (int j = 0; j < 4; ++j) cv[j] = SB4[(tr + 16*j)*(LDP/4) + n4];
#pragma unroll
    for (int i = 0; i < 4; ++i) bv[i] = SA4[(tc + 16*i)*(LDP/4) + n4];
#pragma unroll
    for (int j = 0; j < 4; ++j)
#pragma unroll
      for (int i = 0; i < 4; ++i)
        S[j][i] += cv[j].x*bv[i].x + cv[j].y*bv[i].y + cv[j].z*bv[i].z + cv[j].w*bv[i].w;
  }
  __syncthreads();
  // ---- masked decay -> M in SC; reload X into SA
#pragma unroll
  for (int j = 0; j < 4; ++j) {
    int t = tr + 16*j;
#pragma unroll
    for (int i = 0; i < 4; ++i) {
      int s = tc + 16*i;
      float m = 0.f;
      if (s <= t) m = S[j][i] * __expf(A*(cum[t] - cum[s])) * dts[s];
      SC[t*LDP + s] = m;
    }
  }
  for (int i = tid; i < QC*64; i += 256) {
    int s = i >> 6, j = i & 63;
    int tg = t0 + s;
    SA[s*LDP + j] = (tg < LH) ? xbc[((size_t)b*LH + tg)*CONVD + hd*PDIM + j] : 0.f;
  }
  __syncthreads();
  // ---- Y1 = M X  (tile: t = tr+16j, p = tc*4..+3)
  float4 y1[4];
#pragma unroll
  for (int j = 0; j < 4; ++j) y1[j] = make_float4(0.f,0.f,0.f,0.f);
  const float4* SC4 = (const float4*)SC;
#pragma unroll 2
  for (int s4 = 0; s4 < 16; ++s4) {         // capped unroll
    float4 mj[4], xk[4];
#pragma unroll
    for (int j = 0; j < 4; ++j) mj[j] = SC4[(tr + 16*j)*(LDP/4) + s4];
#pragma unroll
    for (int k = 0; k < 4; ++k) xk[k] = SA4[(s4*4 + k)*(LDP/4) + tc];
#pragma unroll
    for (int j = 0; j < 4; ++j) {
      y1[j].x += mj[j].x*xk[0].x + mj[j].y*xk[1].x + mj[j].z*xk[2].x + mj[j].w*xk[3].x;
      y1[j].y += mj[j].x*xk[0].y + mj[j].y*xk[1].y + mj[j].z*xk[2].y + mj[j].w*xk[3].y;
      y1[j].z += mj[j].x*xk[0].z + mj[j].y*xk[1].z + mj[j].z*xk[2].z + mj[j].w*xk[3].z;
      y1[j].w += mj[j].x*xk[0].w + mj[j].y*xk[1].w + mj[j].z*xk[2].w + mj[j].w*xk[3].w;
    }
  }
  __syncthreads();
  // ---- load HT (flat [n*64+p]) into SC
  size_t hbase = (size_t)blk*4096;
  for (int i = tid; i < 4096; i += 256) SC[(i >> 6)*LDP + (i & 63)] = Hin[hbase + i];
  __syncthreads();
  // ---- Y2 = C H_in^T  (reduction over n)
  float4 y2[4];
#pragma unroll
  for (int j = 0; j < 4; ++j) y2[j] = make_float4(0.f,0.f,0.f,0.f);
#pragma unroll 2
  for (int n4 = 0; n4 < 16; ++n4) {         // capped unroll
    float4 cj[4], hk[4];
#pragma unroll
    for (int j = 0; j < 4; ++j) cj[j] = SB4[(tr + 16*j)*(LDP/4) + n4];
#pragma unroll
    for (int k = 0; k < 4; ++k) hk[k] = SC4[(n4*4 + k)*(LDP/4) + tc];
#pragma unroll
    for (int j = 0; j < 4; ++j) {
      y2[j].x += cj[j].x*hk[0].x + cj[j].y*hk[1].x + cj[j].z*hk[2].x + cj[j].w*hk[3].x;
      y2[j].y += cj[j].x*hk[0].y + cj[j].y*hk[1].y + cj[j].z*hk[2].y + cj[j].w*hk[3].y;
      y2[j].z += cj[j].x*hk[0].z + cj[j].y*hk[1].z + cj[j].z*hk[2].z + cj[j].w*hk[3].z;
      y2[j].w += cj[j].x*hk[0].w + cj[j].y*hk[1].w + cj[j].z*hk[2].w + cj[j].w*hk[3].w;
    }
  }
#pragma unroll
  for (int j = 0; j < 4; ++j) {
    int t = tr + 16*j, tg = t0 + t;
    if (tg < LH) {
      float pr = pref[t];
      float4 o;
      o.x = y1[j].x + pr*y2[j].x;
      o.y = y1[j].y + pr*y2[j].y;
      o.z = y1[j].z + pr*y2[j].z;
      o.w = y1[j].w + pr*y2[j].w;
      *(float4*)(y + ((size_t)b*LH + tg)*DIN + hd*PDIM + tc*4) = o;
    }
  }
}

// ---------------------------------------------------------------- gate + rmsnorm + out_proj
// grid: BATCH*256, block 256. Matmul: thread owns 2 j's x one k-quarter; acc[2][8].
#define TR5 8
__global__ void __launch_bounds__(256) k_out(
    const float* __restrict__ y, const float* __restrict__ xbc,
    const float* __restrict__ zx, const float* __restrict__ Dh,
    const float* __restrict__ nw, const float* __restrict__ ow,
    float* __restrict__ h) {
  const int nblk_l = (LH + TR5 - 1) / TR5;    // 256
  int b = blockIdx.x / nblk_l;
  int l0 = (blockIdx.x % nblk_l) * TR5;
  int t = threadIdx.x;
  __shared__ __align__(16) float yv[TR5][DIN];
  __shared__ float part[4][TR5][DIM];          // 16 KB quarter partials
  __shared__ float red[TR5][4];
  __shared__ float rs[TR5];
  int c = t;
  int hd = c >> 6;
  float dcoef = Dh[hd];
  float nwc = nw[c];
  float v[TR5];
#pragma unroll
  for (int r = 0; r < TR5; ++r) {
    int l = l0 + r;
    float val = 0.f;
    if (l < LH) {
      size_t row = (size_t)b*LH + l;
      float ys = y[row*DIN + c];
      float xh = xbc[row*CONVD + c];
      float z  = zx[row*DPROJ + c];
      val = (ys + dcoef*xh) * siluf_(z);
    }
    v[r] = val;
  }
  int wave = t >> 6, lane = t & 63;
#pragma unroll
  for (int r = 0; r < TR5; ++r) {
    float sq = v[r]*v[r];
    for (int off = 32; off > 0; off >>= 1) sq += __shfl_down(sq, off);
    if (lane == 0) red[r][wave] = sq;
  }
  __syncthreads();
  if (t < TR5) {
    float sm = red[t][0]+red[t][1]+red[t][2]+red[t][3];
    rs[t] = rsqrtf(sm/(float)DIN + 1e-5f);
  }
  __syncthreads();
#pragma unroll
  for (int r = 0; r < TR5; ++r) yv[r][c] = v[r] * rs[r] * nwc;
  __syncthreads();
  // matmul: jp = t&63 -> j in {2jp, 2jp+1}; q = t>>6 -> k in [q*64, q*64+64)
  int jp = t & 63, q = t >> 6;
  int j0 = jp*2;
  float acc[2][TR5];
#pragma unroll
  for (int jj = 0; jj < 2; ++jj)
#pragma unroll
    for (int r = 0; r < TR5; ++r) acc[jj][r] = 0.f;
  const float4* wr0 = (const float4*)(ow + (size_t)j0*DIN + q*64);
  const float4* wr1 = (const float4*)(ow + (size_t)(j0+1)*DIN + q*64);
#pragma unroll 2
  for (int k4 = 0; k4 < 16; ++k4) {
    float4 wa = wr0[k4], wb = wr1[k4];
#pragma unroll
    for (int r = 0; r < TR5; ++r) {
      float4 hv = ((const float4*)&yv[r][q*64])[k4];  // broadcast
      acc[0][r] += wa.x*hv.x + wa.y*hv.y + wa.z*hv.z + wa.w*hv.w;
      acc[1][r] += wb.x*hv.x + wb.y*hv.y + wb.z*hv.z + wb.w*hv.w;
    }
  }
#pragma unroll
  for (int r = 0; r < TR5; ++r) {
    part[q][r][j0]   = acc[0][r];
    part[q][r][j0+1] = acc[1][r];
  }
  __syncthreads();
  if (t < DIM) {
#pragma unroll 2
    for (int r = 0; r < TR5; ++r) {
      int l = l0 + r;
      if (l < LH)
        h[((size_t)b*LH + l)*DIM + t] =
            part[0][r][t] + part[1][r][t] + part[2][r][t] + part[3][r][t];
    }
  }
}

// ---------------------------------------------------------------- final LN + head
__global__ void k_head(const float* __restrict__ h, const float* __restrict__ lnw,
                       const float* __restrict__ lnb, const float* __restrict__ hw,
                       const float* __restrict__ hb, float* __restrict__ out) {
  int b = blockIdx.x; int t = threadIdx.x;
  __shared__ float red[2];
  int wave = t >> 6, lane = t & 63;
  float v = h[((size_t)b*LH + LSEQ)*DIM + t];
  float s = v;
  for (int off = 32; off > 0; off >>= 1) s += __shfl_down(s, off);
  if (lane == 0) red[wave] = s;
  __syncthreads();
  float mean = (red[0]+red[1]) / (float)DIM;
  __syncthreads();
  float d = v - mean; float sq = d*d;
  for (int off = 32; off > 0; off >>= 1) sq += __shfl_down(sq, off);
  if (lane == 0) red[wave] = sq;
  __syncthreads();
  float var = (red[0]+red[1]) / (float)DIM;
  float cn = d*rsqrtf(var + 1e-5f)*lnw[t] + lnb[t];
  float dot = cn*hw[t];
  __syncthreads();
  for (int off = 32; off > 0; off >>= 1) dot += __shfl_down(dot, off);
  if (lane == 0) red[wave] = dot;
  __syncthreads();
  if (t == 0) out[b] = red[0]+red[1] + hb[0];
}

// ---------------------------------------------------------------- h -> d_out copy
__global__ void k_copy(const float* __restrict__ src, float* __restrict__ dst, long n4) {
  long i = (long)blockIdx.x*blockDim.x + threadIdx.x;
  if (i < n4) ((float4*)dst)[i] = ((const float4*)src)[i];
}

extern "C" void kernel_launch(void* const* d_in, const int* in_sizes, int n_in,
                              void* d_out, int out_size, void* d_ws, size_t ws_size,
                              hipStream_t stream) {
  const float* x     = (const float*)d_in[0];
  const float* w1    = (const float*)d_in[1];
  const float* b1    = (const float*)d_in[2];
  const float* w2    = (const float*)d_in[3];
  const float* b2    = (const float*)d_in[4];
  const float* cls   = (const float*)d_in[5];
  const float* inw   = (const float*)d_in[6];   // (4, 644, 128)
  const float* cw    = (const float*)d_in[7];   // (4, 384, 4)
  const float* cb    = (const float*)d_in[8];   // (4, 384)
  const float* dtb   = (const float*)d_in[9];   // (4, 4)
  const float* Alog  = (const float*)d_in[10];  // (4, 4)
  const float* Dh    = (const float*)d_in[11];  // (4, 4)
  const float* nw    = (const float*)d_in[12];  // (4, 256)
  const float* ow    = (const float*)d_in[13];  // (4, 128, 256)
  const float* lnw   = (const float*)d_in[14];
  const float* lnb   = (const float*)d_in[15];
  const float* hw    = (const float*)d_in[16];
  const float* hb    = (const float*)d_in[17];

  float* ws   = (float*)d_ws;
  float* hbuf = ws;                                   // 2,094,080
  float* zx   = hbuf + (size_t)BATCH*LH*DIM;          // 10,535,840
  float* xbc  = zx   + (size_t)BATCH*LH*DPROJ;        // 6,282,240
  float* ybuf = xbc  + (size_t)BATCH*LH*CONVD;        // 4,194,304 (G aliases ybuf)
  float* G    = ybuf;                                 //   (consumed before y written)
  float* Hin  = ybuf + 4194304;                       // 4,194,304
  float* dec  = Hin  + 4194304;                       // 1,024
  // total: 27,301,792 floats = 104.2 MiB

  k_front<<<BATCH*64 + 1, 256, 0, stream>>>(x, w1, b1, w2, b2, cls, hbuf);

  for (int i = 0; i < DEPTH; ++i) {
    k_inproj<<<BATCH*((LH+TR2-1)/TR2), 256, 0, stream>>>(
        hbuf, inw + (size_t)i*DPROJ*DIM, dtb + i*NH, zx);
    {
      long total = (long)BATCH*LH*CONVD;
      k_conv<<<(int)((total + 255)/256), 256, 0, stream>>>(
          zx, cw + (size_t)i*CONVD*4, cb + (size_t)i*CONVD, xbc);
    }
    k_chunk_state<<<BATCH*NH*NCH, 256, 0, stream>>>(zx, xbc, Alog + i*NH, G, dec);
    k_combine<<<BATCH*NH*4, 256, 0, stream>>>(G, dec, Hin);
    k_chunk_out<<<BATCH*NH*NCH, 256, 0, stream>>>(zx, xbc, Alog + i*NH, Hin, ybuf);
    k_out<<<BATCH*((LH+TR5-1)/TR5), 256, 0, stream>>>(
        ybuf, xbc, zx, Dh + i*NH, nw + (size_t)i*DIN, ow + (size_t)i*DIM*DIN, hbuf);
  }

  k_head<<<BATCH, 128, 0, stream>>>(hbuf, lnw, lnb, hw, hb, (float*)d_out);
  {
    long n4 = (long)BATCH*LH*DIM/4;
    k_copy<<<(int)((n4 + 255)/256), 256, 0, stream>>>(hbuf, (float*)d_out + 8, n4);
  }
}

// Round 7
// 908.596 us; speedup vs baseline: 1.2870x; 1.1119x over previous
//
#include <hip/hip_runtime.h>
#include <math.h>

// Shapes (fixed by setup_inputs)
#define BATCH 8
#define TSEQ 2048
#define CIN 3
#define WIN 5
#define LSEQ 2044          // T - WIN + 1
#define LH 2045            // LSEQ + 1 (cls token appended)
#define DIM 128
#define DEPTH 4
#define DIN 256            // d_inner
#define NH 4               // heads
#define PDIM 64            // headdim
#define NSTATE 64          // d_state
#define CONVD 384          // d_inner + 2*d_state
#define DPROJ 644          // 2*d_inner + 2*d_state + nheads
#define QC 64              // chunk length
#define NCH 32             // number of chunks (32*64 = 2048 >= 2045)
#define LDP 68             // padded LDS row stride (17 float4s; bank-spread)
#define FTR 32             // tokens per k_front block

__device__ __forceinline__ float sigmoidf_(float x){ return 1.f/(1.f+__expf(-x)); }
__device__ __forceinline__ float siluf_(float x){ return x*sigmoidf_(x); }

// ---------------------------------------------------------------- weight transpose
// src[layer][R][C] -> dst[layer][C][R]. grid (ceil(C/64), ceil(R/64), layers), block 256.
__global__ void __launch_bounds__(256) k_transpose(
    const float* __restrict__ src, float* __restrict__ dst, int R, int C) {
  __shared__ float tile[64][65];
  const float* s = src + (size_t)blockIdx.z*R*C;
  float* d = dst + (size_t)blockIdx.z*R*C;
  int r0 = blockIdx.y*64, c0 = blockIdx.x*64;
  int tx = threadIdx.x & 63, ty = threadIdx.x >> 6;
  for (int rr = ty; rr < 64; rr += 4) {
    int r = r0 + rr, c = c0 + tx;
    if (r < R && c < C) tile[rr][tx] = s[(size_t)r*C + c];
  }
  __syncthreads();
  for (int cc = ty; cc < 64; cc += 4) {
    int c = c0 + cc, r = r0 + tx;
    if (c < C && r < R) d[(size_t)c*R + r] = tile[tx][cc];
  }
}

// ---------------------------------------------------------------- front MLP
// grid: BATCH*64 + 1, block 256. 32 tokens/block; w2 half-rows register-cached.
__global__ void __launch_bounds__(256) k_front(
    const float* __restrict__ x, const float* __restrict__ w1,
    const float* __restrict__ b1, const float* __restrict__ w2,
    const float* __restrict__ b2, const float* __restrict__ cls,
    float* __restrict__ h) {
  int t = threadIdx.x;
  if (blockIdx.x == BATCH*64) {              // cls rows
    if (t < DIM) {
      float cv = cls[t];
      for (int b = 0; b < BATCH; ++b) h[((size_t)b*LH + LSEQ)*DIM + t] = cv;
    }
    return;
  }
  int b = blockIdx.x >> 6;
  int c0 = (blockIdx.x & 63) * FTR;
  __shared__ float xs[(FTR+4)*CIN];                  // 108
  __shared__ float w1s[DIM*17];                      // stride 17: 2-way banks = free
  __shared__ __align__(16) float h1s[FTR][DIM];      // 16 KB
  __shared__ float part[FTR][DIM][2];                // 32 KB
  for (int i = t; i < (FTR+4)*CIN; i += 256) {
    int row = c0 + i/3, ch = i - (i/3)*3;
    xs[i] = (row < TSEQ) ? x[(size_t)b*TSEQ*CIN + (size_t)row*CIN + ch] : 0.f;
  }
  for (int i = t; i < DIM*15; i += 256) {
    int j = i/15, k = i - j*15;
    w1s[j*17+k] = w1[i];
  }
  __syncthreads();
  {
    int j = t & 127, rh = t >> 7;
    float bias = b1[j];
    const float* wr = &w1s[j*17];
    for (int r = rh*16; r < rh*16+16; ++r) {
      float a = bias;
#pragma unroll
      for (int k = 0; k < 15; ++k) a += xs[r*3+k]*wr[k];
      h1s[r][j] = 0.5f*a*(1.f + erff(a*0.70710678118654752f));  // exact gelu
    }
  }
  __syncthreads();
  {
    int j = t & 127, hf = t >> 7;
    float4 wv[16];                                   // 64-float w2 half-row in regs
    const float4* w2r = (const float4*)(w2 + (size_t)j*DIM + hf*64);
#pragma unroll
    for (int k4 = 0; k4 < 16; ++k4) wv[k4] = w2r[k4];
#pragma unroll 2
    for (int r = 0; r < FTR; ++r) {
      const float4* hr = (const float4*)&h1s[r][hf*64];
      float acc = 0.f;
#pragma unroll
      for (int k4 = 0; k4 < 16; ++k4) {
        float4 hv = hr[k4];                          // broadcast read: free
        acc += wv[k4].x*hv.x + wv[k4].y*hv.y + wv[k4].z*hv.z + wv[k4].w*hv.w;
      }
      part[r][j][hf] = acc;
    }
  }
  __syncthreads();
  if (t < DIM) {
    float bias = b2[t];
    for (int r = 0; r < FTR; ++r) {
      int l = c0 + r;
      if (l < LSEQ) h[((size_t)b*LH + l)*DIM + t] = part[r][t][0] + part[r][t][1] + bias;
    }
  }
}

// ---------------------------------------------------------------- in_proj (+ dt softplus)
// grid: BATCH*128, block 256. J=3 register tile; weights read COALESCED from wT[k][j].
// NOTE (R5): epilogue must be compile-time unrolled (dynamic index -> scratch spill).
// NOTE (R6): w[j][k] reads had lane stride 512B (64 lines/instr) -> pre-transposed.
#define TR2 16
__global__ void __launch_bounds__(256) k_inproj(
    const float* __restrict__ h, const float* __restrict__ wT,
    const float* __restrict__ dtb, float* __restrict__ zx) {
  const int nblk_l = (LH + TR2 - 1) / TR2;   // 128
  int b = blockIdx.x / nblk_l;
  int l0 = (blockIdx.x % nblk_l) * TR2;
  int t = threadIdx.x;
  __shared__ __align__(16) float hs[TR2][DIM];
  for (int i = t; i < TR2*DIM; i += 256) {
    int r = i >> 7, k = i & 127;
    int l = l0 + r;
    hs[r][k] = (l < LH) ? h[((size_t)b*LH + l)*DIM + k] : 0.f;
  }
  __syncthreads();
  bool j2ok = (t < DPROJ - 512);             // t < 132
  int t2 = j2ok ? t + 512 : t;
  float acc[3][TR2];
#pragma unroll
  for (int jj = 0; jj < 3; ++jj)
#pragma unroll
    for (int r = 0; r < TR2; ++r) acc[jj][r] = 0.f;
#pragma unroll 2
  for (int k4 = 0; k4 < 32; ++k4) {          // capped unroll: VGPRs < spill cliff
    float wa[4], wb[4], wc[4];
#pragma unroll
    for (int c = 0; c < 4; ++c) {
      const float* wrow = wT + (size_t)(k4*4 + c)*DPROJ;
      wa[c] = wrow[t];                       // lane stride 4B: coalesced
      wb[c] = wrow[t + 256];
      wc[c] = wrow[t2];
    }
#pragma unroll
    for (int r = 0; r < TR2; ++r) {
      float4 hv = ((const float4*)&hs[r][0])[k4];   // broadcast read
      acc[0][r] += wa[0]*hv.x + wa[1]*hv.y + wa[2]*hv.z + wa[3]*hv.w;
      acc[1][r] += wb[0]*hv.x + wb[1]*hv.y + wb[2]*hv.z + wb[3]*hv.w;
      acc[2][r] += wc[0]*hv.x + wc[1]*hv.y + wc[2]*hv.z + wc[3]*hv.w;
    }
  }
  bool isdt = j2ok && (t >= 128);            // j2 = t+512 >= 640
  float bias2 = isdt ? dtb[t - 128] : 0.f;
#pragma unroll
  for (int r = 0; r < TR2; ++r) {            // compile-time: acc stays in VGPRs
    int l = l0 + r;
    if (l >= LH) continue;
    size_t row = ((size_t)b*LH + l)*DPROJ;
    zx[row + t]       = acc[0][r];
    zx[row + t + 256] = acc[1][r];
    if (j2ok) {
      float v = acc[2][r];
      if (isdt) { v += bias2; v = (v > 20.f) ? v : log1pf(__expf(v)); } // softplus
      zx[row + t + 512] = v;
    }
  }
}

// ---------------------------------------------------------------- causal dwconv + silu
__global__ void k_conv(const float* __restrict__ zx, const float* __restrict__ cw,
                       const float* __restrict__ cb, float* __restrict__ xbc) {
  size_t idx = (size_t)blockIdx.x*blockDim.x + threadIdx.x;
  const size_t total = (size_t)BATCH*LH*CONVD;
  if (idx >= total) return;
  int c = (int)(idx % CONVD);
  size_t bl = idx / CONVD;
  int l = (int)(bl % LH); int b = (int)(bl / LH);
  float acc = cb[c];
#pragma unroll
  for (int k = 0; k < 4; ++k) {
    int tin = l - 3 + k;
    if (tin >= 0) acc += zx[((size_t)b*LH + tin)*DPROJ + DIN + c] * cw[c*4 + k];
  }
  xbc[idx] = siluf_(acc);
}

// ---------------------------------------------------------------- chunked SSD, phase A:
// per-chunk local state G (stored transposed: flat[n*64+p] = H_local[p][n]) + chunk decay
// grid: BATCH*NH*NCH = 1024, block 256
__global__ void __launch_bounds__(256) k_chunk_state(
    const float* __restrict__ zx, const float* __restrict__ xbc,
    const float* __restrict__ A_log, float* __restrict__ G, float* __restrict__ dec) {
  int blk = blockIdx.x;
  int c = blk & (NCH-1), hd = (blk >> 5) & 3, b = blk >> 7;
  int t0 = c*QC;
  int tid = threadIdx.x;
  float A = -__expf(A_log[hd]);
  __shared__ float xs[QC*PDIM];     // [s][p]
  __shared__ float Bs[QC*NSTATE];   // [s][n]
  __shared__ float coef[QC];
  if (tid < 64) {
    int tg = t0 + tid;
    float dtv = (tg < LH) ? zx[((size_t)b*LH + tg)*DPROJ + 640 + hd] : 0.f;
    float s = dtv;
#pragma unroll
    for (int off = 1; off < 64; off <<= 1) {
      float u = __shfl_up(s, off);
      if (tid >= off) s += u;
    }
    float cq = __shfl(s, 63);
    coef[tid] = __expf(A*(cq - s)) * dtv;
    if (tid == 63) dec[blk] = __expf(A * s);
  }
  for (int i = tid; i < QC*64; i += 256) {
    int s = i >> 6, j = i & 63;
    int tg = t0 + s;
    float xv = 0.f, bv = 0.f;
    if (tg < LH) {
      size_t row = ((size_t)b*LH + tg)*CONVD;
      xv = xbc[row + hd*PDIM + j];
      bv = xbc[row + DIN + j];
    }
    xs[i] = xv; Bs[i] = bv;
  }
  __syncthreads();
  int n = tid >> 2, q = tid & 3;            // thread owns (n, p in [q*16, q*16+16))
  float4 acc[4];
#pragma unroll
  for (int i4 = 0; i4 < 4; ++i4) acc[i4] = make_float4(0.f,0.f,0.f,0.f);
  const float4* xs4 = (const float4*)xs;
#pragma unroll 4
  for (int s = 0; s < QC; ++s) {            // capped unroll: keep VGPRs < spill
    float cb_ = coef[s] * Bs[s*64 + n];
#pragma unroll
    for (int i4 = 0; i4 < 4; ++i4) {
      float4 xv = xs4[s*16 + q*4 + i4];
      acc[i4].x += cb_*xv.x; acc[i4].y += cb_*xv.y;
      acc[i4].z += cb_*xv.z; acc[i4].w += cb_*xv.w;
    }
  }
  float4* gp = (float4*)(G + (size_t)blk*4096 + n*64 + q*16);
#pragma unroll
  for (int i4 = 0; i4 < 4; ++i4) gp[i4] = acc[i4];
}

// ---------------------------------------------------------------- phase B: inter-chunk
// recurrence. Stores carry-in state per chunk. grid 32*4=128, block 256, 4 floats/thread
__global__ void __launch_bounds__(256) k_combine(
    const float* __restrict__ G, const float* __restrict__ dec, float* __restrict__ Hin) {
  int bh = blockIdx.x >> 2, esp = blockIdx.x & 3;
  int e = esp*1024 + threadIdx.x*4;
  size_t base0 = (size_t)bh*NCH*4096 + e;
  float4 H = make_float4(0.f,0.f,0.f,0.f);
  float4 g = *(const float4*)(G + base0);
  float d = dec[bh*NCH];
  for (int c = 0; c < NCH; ++c) {
    float4 gn = make_float4(0.f,0.f,0.f,0.f); float dn = 0.f;
    if (c + 1 < NCH) {
      gn = *(const float4*)(G + base0 + (size_t)(c+1)*4096);
      dn = dec[bh*NCH + c + 1];
    }
    *(float4*)(Hin + base0 + (size_t)c*4096) = H;   // carry-in for chunk c
    H.x = H.x*d + g.x; H.y = H.y*d + g.y; H.z = H.z*d + g.z; H.w = H.w*d + g.w;
    g = gn; d = dn;
  }
}

// ---------------------------------------------------------------- phase C: chunk output
// y[t][p] = sum_{s<=t} exp(A(cum_t-cum_s))dt_s (C_t.B_s) x_s[p] + exp(A cum_t) C_t.H_in[p,:]
// grid 1024, block 256. Tiles: t = tr+16j (tr=tid>>4), p = tc*4..+3 (tc=tid&15), s' = tc+16i
__global__ void __launch_bounds__(256) k_chunk_out(
    const float* __restrict__ zx, const float* __restrict__ xbc,
    const float* __restrict__ A_log, const float* __restrict__ Hin,
    float* __restrict__ y) {
  int blk = blockIdx.x;
  int c = blk & (NCH-1), hd = (blk >> 5) & 3, b = blk >> 7;
  int t0 = c*QC;
  int tid = threadIdx.x;
  int tr = tid >> 4, tc = tid & 15;
  float A = -__expf(A_log[hd]);
  __shared__ __align__(16) float SA[QC*LDP];   // B, then X
  __shared__ __align__(16) float SB[QC*LDP];   // C
  __shared__ __align__(16) float SC[QC*LDP];   // M, then HT
  __shared__ float cum[QC], dts[QC], pref[QC];
  if (tid < 64) {
    int tg = t0 + tid;
    float dtv = (tg < LH) ? zx[((size_t)b*LH + tg)*DPROJ + 640 + hd] : 0.f;
    float s = dtv;
#pragma unroll
    for (int off = 1; off < 64; off <<= 1) {
      float u = __shfl_up(s, off);
      if (tid >= off) s += u;
    }
    dts[tid] = dtv; cum[tid] = s; pref[tid] = __expf(A*s);
  }
  for (int i = tid; i < QC*64; i += 256) {
    int s = i >> 6, j = i & 63;
    int tg = t0 + s;
    float bv = 0.f, cv = 0.f;
    if (tg < LH) {
      size_t row = ((size_t)b*LH + tg)*CONVD;
      bv = xbc[row + DIN + j];
      cv = xbc[row + DIN + NSTATE + j];
    }
    SA[s*LDP + j] = bv; SB[s*LDP + j] = cv;
  }
  __syncthreads();
  // ---- S = C B^T  (tile: t = tr+16j, s' = tc+16i)
  float S[4][4];
#pragma unroll
  for (int j = 0; j < 4; ++j)
#pragma unroll
    for (int i = 0; i < 4; ++i) S[j][i] = 0.f;
  const float4* SA4 = (const float4*)SA;
  const float4* SB4 = (const float4*)SB;
#pragma unroll 2
  for (int n4 = 0; n4 < 16; ++n4) {         // capped unroll: keep VGPRs < spill
    float4 cv[4], bv[4];
#pragma unroll
    for (int j = 0; j < 4; ++j) cv[j] = SB4[(tr + 16*j)*(LDP/4) + n4];
#pragma unroll
    for (int i = 0; i < 4; ++i) bv[i] = SA4[(tc + 16*i)*(LDP/4) + n4];
#pragma unroll
    for (int j = 0; j < 4; ++j)
#pragma unroll
      for (int i = 0; i < 4; ++i)
        S[j][i] += cv[j].x*bv[i].x + cv[j].y*bv[i].y + cv[j].z*bv[i].z + cv[j].w*bv[i].w;
  }
  __syncthreads();
  // ---- masked decay -> M in SC; reload X into SA
#pragma unroll
  for (int j = 0; j < 4; ++j) {
    int t = tr + 16*j;
#pragma unroll
    for (int i = 0; i < 4; ++i) {
      int s = tc + 16*i;
      float m = 0.f;
      if (s <= t) m = S[j][i] * __expf(A*(cum[t] - cum[s])) * dts[s];
      SC[t*LDP + s] = m;
    }
  }
  for (int i = tid; i < QC*64; i += 256) {
    int s = i >> 6, j = i & 63;
    int tg = t0 + s;
    SA[s*LDP + j] = (tg < LH) ? xbc[((size_t)b*LH + tg)*CONVD + hd*PDIM + j] : 0.f;
  }
  __syncthreads();
  // ---- Y1 = M X  (tile: t = tr+16j, p = tc*4..+3)
  float4 y1[4];
#pragma unroll
  for (int j = 0; j < 4; ++j) y1[j] = make_float4(0.f,0.f,0.f,0.f);
  const float4* SC4 = (const float4*)SC;
#pragma unroll 2
  for (int s4 = 0; s4 < 16; ++s4) {         // capped unroll
    float4 mj[4], xk[4];
#pragma unroll
    for (int j = 0; j < 4; ++j) mj[j] = SC4[(tr + 16*j)*(LDP/4) + s4];
#pragma unroll
    for (int k = 0; k < 4; ++k) xk[k] = SA4[(s4*4 + k)*(LDP/4) + tc];
#pragma unroll
    for (int j = 0; j < 4; ++j) {
      y1[j].x += mj[j].x*xk[0].x + mj[j].y*xk[1].x + mj[j].z*xk[2].x + mj[j].w*xk[3].x;
      y1[j].y += mj[j].x*xk[0].y + mj[j].y*xk[1].y + mj[j].z*xk[2].y + mj[j].w*xk[3].y;
      y1[j].z += mj[j].x*xk[0].z + mj[j].y*xk[1].z + mj[j].z*xk[2].z + mj[j].w*xk[3].z;
      y1[j].w += mj[j].x*xk[0].w + mj[j].y*xk[1].w + mj[j].z*xk[2].w + mj[j].w*xk[3].w;
    }
  }
  __syncthreads();
  // ---- load HT (flat [n*64+p]) into SC
  size_t hbase = (size_t)blk*4096;
  for (int i = tid; i < 4096; i += 256) SC[(i >> 6)*LDP + (i & 63)] = Hin[hbase + i];
  __syncthreads();
  // ---- Y2 = C H_in^T  (reduction over n)
  float4 y2[4];
#pragma unroll
  for (int j = 0; j < 4; ++j) y2[j] = make_float4(0.f,0.f,0.f,0.f);
#pragma unroll 2
  for (int n4 = 0; n4 < 16; ++n4) {         // capped unroll
    float4 cj[4], hk[4];
#pragma unroll
    for (int j = 0; j < 4; ++j) cj[j] = SB4[(tr + 16*j)*(LDP/4) + n4];
#pragma unroll
    for (int k = 0; k < 4; ++k) hk[k] = SC4[(n4*4 + k)*(LDP/4) + tc];
#pragma unroll
    for (int j = 0; j < 4; ++j) {
      y2[j].x += cj[j].x*hk[0].x + cj[j].y*hk[1].x + cj[j].z*hk[2].x + cj[j].w*hk[3].x;
      y2[j].y += cj[j].x*hk[0].y + cj[j].y*hk[1].y + cj[j].z*hk[2].y + cj[j].w*hk[3].y;
      y2[j].z += cj[j].x*hk[0].z + cj[j].y*hk[1].z + cj[j].z*hk[2].z + cj[j].w*hk[3].z;
      y2[j].w += cj[j].x*hk[0].w + cj[j].y*hk[1].w + cj[j].z*hk[2].w + cj[j].w*hk[3].w;
    }
  }
#pragma unroll
  for (int j = 0; j < 4; ++j) {
    int t = tr + 16*j, tg = t0 + t;
    if (tg < LH) {
      float pr = pref[t];
      float4 o;
      o.x = y1[j].x + pr*y2[j].x;
      o.y = y1[j].y + pr*y2[j].y;
      o.z = y1[j].z + pr*y2[j].z;
      o.w = y1[j].w + pr*y2[j].w;
      *(float4*)(y + ((size_t)b*LH + tg)*DIN + hd*PDIM + tc*4) = o;
    }
  }
}

// ---------------------------------------------------------------- gate + rmsnorm + out_proj
// grid: BATCH*256, block 256. Thread owns 2 j's x one k-quarter; weights COALESCED
// via owT[k][j] (float2 loads, lane stride 8B).
#define TR5 8
__global__ void __launch_bounds__(256) k_out(
    const float* __restrict__ y, const float* __restrict__ xbc,
    const float* __restrict__ zx, const float* __restrict__ Dh,
    const float* __restrict__ nw, const float* __restrict__ owT,
    float* __restrict__ h) {
  const int nblk_l = (LH + TR5 - 1) / TR5;    // 256
  int b = blockIdx.x / nblk_l;
  int l0 = (blockIdx.x % nblk_l) * TR5;
  int t = threadIdx.x;
  __shared__ __align__(16) float yv[TR5][DIN];
  __shared__ float part[4][TR5][DIM];          // 16 KB quarter partials
  __shared__ float red[TR5][4];
  __shared__ float rs[TR5];
  int c = t;
  int hd = c >> 6;
  float dcoef = Dh[hd];
  float nwc = nw[c];
  float v[TR5];
#pragma unroll
  for (int r = 0; r < TR5; ++r) {
    int l = l0 + r;
    float val = 0.f;
    if (l < LH) {
      size_t row = (size_t)b*LH + l;
      float ys = y[row*DIN + c];
      float xh = xbc[row*CONVD + c];
      float z  = zx[row*DPROJ + c];
      val = (ys + dcoef*xh) * siluf_(z);
    }
    v[r] = val;
  }
  int wave = t >> 6, lane = t & 63;
#pragma unroll
  for (int r = 0; r < TR5; ++r) {
    float sq = v[r]*v[r];
    for (int off = 32; off > 0; off >>= 1) sq += __shfl_down(sq, off);
    if (lane == 0) red[r][wave] = sq;
  }
  __syncthreads();
  if (t < TR5) {
    float sm = red[t][0]+red[t][1]+red[t][2]+red[t][3];
    rs[t] = rsqrtf(sm/(float)DIN + 1e-5f);
  }
  __syncthreads();
#pragma unroll
  for (int r = 0; r < TR5; ++r) yv[r][c] = v[r] * rs[r] * nwc;
  __syncthreads();
  // matmul: jp = t&63 -> j in {2jp, 2jp+1}; q = t>>6 -> k in [q*64, q*64+64)
  int jp = t & 63, q = t >> 6;
  int j0 = jp*2;
  float acc[2][TR5];
#pragma unroll
  for (int jj = 0; jj < 2; ++jj)
#pragma unroll
    for (int r = 0; r < TR5; ++r) acc[jj][r] = 0.f;
  const float* wtb = owT + (size_t)q*64*DIM + j0;   // rows q*64.., row len 128
#pragma unroll 2
  for (int k4 = 0; k4 < 16; ++k4) {
    float2 w0 = *(const float2*)(wtb + (k4*4+0)*DIM);   // coalesced (8B/lane)
    float2 w1 = *(const float2*)(wtb + (k4*4+1)*DIM);
    float2 w2_ = *(const float2*)(wtb + (k4*4+2)*DIM);
    float2 w3 = *(const float2*)(wtb + (k4*4+3)*DIM);
#pragma unroll
    for (int r = 0; r < TR5; ++r) {
      float4 hv = ((const float4*)&yv[r][q*64])[k4];  // broadcast
      acc[0][r] += w0.x*hv.x + w1.x*hv.y + w2_.x*hv.z + w3.x*hv.w;
      acc[1][r] += w0.y*hv.x + w1.y*hv.y + w2_.y*hv.z + w3.y*hv.w;
    }
  }
#pragma unroll
  for (int r = 0; r < TR5; ++r) {
    part[q][r][j0]   = acc[0][r];
    part[q][r][j0+1] = acc[1][r];
  }
  __syncthreads();
  if (t < DIM) {
#pragma unroll 2
    for (int r = 0; r < TR5; ++r) {
      int l = l0 + r;
      if (l < LH)
        h[((size_t)b*LH + l)*DIM + t] =
            part[0][r][t] + part[1][r][t] + part[2][r][t] + part[3][r][t];
    }
  }
}

// ---------------------------------------------------------------- final LN + head
__global__ void k_head(const float* __restrict__ h, const float* __restrict__ lnw,
                       const float* __restrict__ lnb, const float* __restrict__ hw,
                       const float* __restrict__ hb, float* __restrict__ out) {
  int b = blockIdx.x; int t = threadIdx.x;
  __shared__ float red[2];
  int wave = t >> 6, lane = t & 63;
  float v = h[((size_t)b*LH + LSEQ)*DIM + t];
  float s = v;
  for (int off = 32; off > 0; off >>= 1) s += __shfl_down(s, off);
  if (lane == 0) red[wave] = s;
  __syncthreads();
  float mean = (red[0]+red[1]) / (float)DIM;
  __syncthreads();
  float d = v - mean; float sq = d*d;
  for (int off = 32; off > 0; off >>= 1) sq += __shfl_down(sq, off);
  if (lane == 0) red[wave] = sq;
  __syncthreads();
  float var = (red[0]+red[1]) / (float)DIM;
  float cn = d*rsqrtf(var + 1e-5f)*lnw[t] + lnb[t];
  float dot = cn*hw[t];
  __syncthreads();
  for (int off = 32; off > 0; off >>= 1) dot += __shfl_down(dot, off);
  if (lane == 0) red[wave] = dot;
  __syncthreads();
  if (t == 0) out[b] = red[0]+red[1] + hb[0];
}

// ---------------------------------------------------------------- h -> d_out copy
__global__ void k_copy(const float* __restrict__ src, float* __restrict__ dst, long n4) {
  long i = (long)blockIdx.x*blockDim.x + threadIdx.x;
  if (i < n4) ((float4*)dst)[i] = ((const float4*)src)[i];
}

extern "C" void kernel_launch(void* const* d_in, const int* in_sizes, int n_in,
                              void* d_out, int out_size, void* d_ws, size_t ws_size,
                              hipStream_t stream) {
  const float* x     = (const float*)d_in[0];
  const float* w1    = (const float*)d_in[1];
  const float* b1    = (const float*)d_in[2];
  const float* w2    = (const float*)d_in[3];
  const float* b2    = (const float*)d_in[4];
  const float* cls   = (const float*)d_in[5];
  const float* inw   = (const float*)d_in[6];   // (4, 644, 128)
  const float* cw    = (const float*)d_in[7];   // (4, 384, 4)
  const float* cb    = (const float*)d_in[8];   // (4, 384)
  const float* dtb   = (const float*)d_in[9];   // (4, 4)
  const float* Alog  = (const float*)d_in[10];  // (4, 4)
  const float* Dh    = (const float*)d_in[11];  // (4, 4)
  const float* nw    = (const float*)d_in[12];  // (4, 256)
  const float* ow    = (const float*)d_in[13];  // (4, 128, 256)
  const float* lnw   = (const float*)d_in[14];
  const float* lnb   = (const float*)d_in[15];
  const float* hw    = (const float*)d_in[16];
  const float* hb    = (const float*)d_in[17];

  float* ws   = (float*)d_ws;
  float* hbuf = ws;                                   // 2,094,080
  float* zx   = hbuf + (size_t)BATCH*LH*DIM;          // 10,535,840
  float* xbc  = zx   + (size_t)BATCH*LH*DPROJ;        // 6,282,240
  float* ybuf = xbc  + (size_t)BATCH*LH*CONVD;        // 4,194,304 (G aliases ybuf)
  float* G    = ybuf;                                 //   (consumed before y written)
  float* Hin  = ybuf + 4194304;                       // 4,194,304
  float* dec  = Hin  + 4194304;                       // 1,024
  float* inwT = dec  + 1024;                          // 4*128*644 = 329,728
  float* owT  = inwT + 329728;                        // 4*256*128 = 131,072
  // total: 27,762,592 floats = 111.1 MiB

  k_transpose<<<dim3(2,11,4), 256, 0, stream>>>(inw, inwT, DPROJ, DIM); // [644][128]->[128][644]
  k_transpose<<<dim3(4,2,4),  256, 0, stream>>>(ow,  owT,  DIM, DIN);  // [128][256]->[256][128]

  k_front<<<BATCH*64 + 1, 256, 0, stream>>>(x, w1, b1, w2, b2, cls, hbuf);

  for (int i = 0; i < DEPTH; ++i) {
    k_inproj<<<BATCH*((LH+TR2-1)/TR2), 256, 0, stream>>>(
        hbuf, inwT + (size_t)i*DPROJ*DIM, dtb + i*NH, zx);
    {
      long total = (long)BATCH*LH*CONVD;
      k_conv<<<(int)((total + 255)/256), 256, 0, stream>>>(
          zx, cw + (size_t)i*CONVD*4, cb + (size_t)i*CONVD, xbc);
    }
    k_chunk_state<<<BATCH*NH*NCH, 256, 0, stream>>>(zx, xbc, Alog + i*NH, G, dec);
    k_combine<<<BATCH*NH*4, 256, 0, stream>>>(G, dec, Hin);
    k_chunk_out<<<BATCH*NH*NCH, 256, 0, stream>>>(zx, xbc, Alog + i*NH, Hin, ybuf);
    k_out<<<BATCH*((LH+TR5-1)/TR5), 256, 0, stream>>>(
        ybuf, xbc, zx, Dh + i*NH, nw + (size_t)i*DIN, owT + (size_t)i*DIM*DIN, hbuf);
  }

  k_head<<<BATCH, 128, 0, stream>>>(hbuf, lnw, lnb, hw, hb, (float*)d_out);
  {
    long n4 = (long)BATCH*LH*DIM/4;
    k_copy<<<(int)((n4 + 255)/256), 256, 0, stream>>>(hbuf, (float*)d_out + 8, n4);
  }
}